// Round 5
// baseline (214.618 us; speedup 1.0000x reference)
//
#include <hip/hip_runtime.h>
#include <hip/hip_bf16.h>

#define Cc 64
#define Hc 128
#define Wc 128
#define HWc (Hc * Wc)
#define Bc 4

typedef __attribute__((ext_vector_type(8))) short short8;
typedef __attribute__((ext_vector_type(4))) float float4v;

static __device__ __forceinline__ unsigned short f2bu(float f) {
    __hip_bfloat16 h = __float2bfloat16(f);
    return *(unsigned short*)&h;
}
static __device__ __forceinline__ float bulo(unsigned int u) {
    return __uint_as_float((u & 0xffffu) << 16);
}
static __device__ __forceinline__ float buhi(unsigned int u) {
    return __uint_as_float(u & 0xffff0000u);
}
static __device__ __forceinline__ unsigned int pk2(float a, float b) {
    return (unsigned int)f2bu(a) | ((unsigned int)f2bu(b) << 16);
}

// ---------------------------------------------------------------------------
// prep: blocks 0..255 cvt (float4-vectorized, 4 px/thread),
//       256..327 weight pack (72 blocks), 328..331 lp weights, 332 zpage.
// ---------------------------------------------------------------------------
__global__ __launch_bounds__(256) void prep_k(
    const float* __restrict__ x, const float* __restrict__ kf,
    const float* __restrict__ fw1, const float* __restrict__ fw2,
    const float* __restrict__ mw1, const float* __restrict__ mw2,
    const float* __restrict__ lw1, const float* __restrict__ lw2,
    unsigned short* __restrict__ xb, unsigned short* __restrict__ kfb,
    unsigned short* __restrict__ wbase, unsigned short* __restrict__ zpage)
{
    const int bid = blockIdx.x;
    const int tid = threadIdx.x;

    if (bid < 256) {
        // gid: [tensor:1][b:2][chalf:1][px4:12]
        const int gid    = bid * 256 + tid;
        const int tensor = gid >> 15;
        const int b      = (gid >> 13) & 3;
        const int chalf  = (gid >> 12) & 1;
        const int px     = (gid & 4095) * 4;
        const bool isx   = (tensor == 0);
        const float* s = (isx ? x : kf) + ((size_t)(b * Cc + chalf * 32)) * HWc + px;
        unsigned short* d = (isx ? xb : kfb) + ((size_t)((size_t)b * HWc + px)) * Cc + chalf * 32;
#pragma unroll
        for (int c8 = 0; c8 < 4; ++c8) {
            unsigned int pk[4][4];   // [px][jp]
#pragma unroll
            for (int jp = 0; jp < 4; ++jp) {
                float4 v0 = *(const float4*)(s + (size_t)(c8 * 8 + jp * 2 + 0) * HWc);
                float4 v1 = *(const float4*)(s + (size_t)(c8 * 8 + jp * 2 + 1) * HWc);
                if (isx) {
                    v0.x = fmaxf(v0.x, 0.f); v0.y = fmaxf(v0.y, 0.f);
                    v0.z = fmaxf(v0.z, 0.f); v0.w = fmaxf(v0.w, 0.f);
                    v1.x = fmaxf(v1.x, 0.f); v1.y = fmaxf(v1.y, 0.f);
                    v1.z = fmaxf(v1.z, 0.f); v1.w = fmaxf(v1.w, 0.f);
                }
                pk[0][jp] = pk2(v0.x, v1.x);
                pk[1][jp] = pk2(v0.y, v1.y);
                pk[2][jp] = pk2(v0.z, v1.z);
                pk[3][jp] = pk2(v0.w, v1.w);
            }
#pragma unroll
            for (int i = 0; i < 4; ++i)
                *(uint4*)(d + (size_t)i * Cc + c8 * 8) =
                    make_uint4(pk[i][0], pk[i][1], pk[i][2], pk[i][3]);
        }
    } else if (bid < 328) {                          // 72 weight-pack blocks
        const int wbid  = bid - 256;
        const int which = wbid / 18;
        const float* w = (which == 0) ? fw1 : (which == 1) ? fw2 : (which == 2) ? mw1 : mw2;
        unsigned short* wb = wbase + (size_t)which * 36864;
        const int g = (wbid % 18) * 256 + tid;
        if (g >= 4608) return;
        const int lane = g & 63;
        const int smt  = g >> 6;
        const int s    = smt >> 2;
        const int mt   = smt & 3;
        const int co   = mt * 16 + (lane & 15);
        const int kb   = s * 32 + (lane >> 4) * 8;
        unsigned int pk[4];
#pragma unroll
        for (int jp = 0; jp < 4; ++jp) {
            int k0 = kb + jp * 2, k1 = k0 + 1;
            float v0 = w[((size_t)co * Cc + (k0 & 63)) * 9 + (k0 >> 6)];
            float v1 = w[((size_t)co * Cc + (k1 & 63)) * 9 + (k1 >> 6)];
            pk[jp] = pk2(v0, v1);
        }
        *(uint4*)(wb + (size_t)g * 8) = make_uint4(pk[0], pk[1], pk[2], pk[3]);
    } else if (bid < 332) {                          // 4 lp-weight blocks
        const int wbid  = bid - 328;
        const int which = wbid >> 1;
        const float* w = which ? lw2 : lw1;
        const int Cout = which ? 49 : 64;
        unsigned short* wb = wbase + 4 * 36864 + (size_t)which * 4096;
        const int g = (wbid & 1) * 256 + tid;
        const int lane = g & 63;
        const int smt  = g >> 6;
        const int s    = smt >> 2;
        const int mt   = smt & 3;
        const int co   = mt * 16 + (lane & 15);
        const int kb   = s * 32 + (lane >> 4) * 8;
        unsigned int pk[4];
#pragma unroll
        for (int jp = 0; jp < 4; ++jp) {
            int k0 = kb + jp * 2, k1 = k0 + 1;
            float v0 = (co < Cout) ? w[(size_t)co * Cc + k0] : 0.f;
            float v1 = (co < Cout) ? w[(size_t)co * Cc + k1] : 0.f;
            pk[jp] = pk2(v0, v1);
        }
        *(uint4*)(wb + (size_t)g * 8) = make_uint4(pk[0], pk[1], pk[2], pk[3]);
    } else {
        // 8 KB zero page for direct-conv boundary reads
        uint4 z = make_uint4(0u, 0u, 0u, 0u);
        ((uint4*)zpage)[tid] = z;
        ((uint4*)zpage)[256 + tid] = z;
    }
}

// ---------------------------------------------------------------------------
// Direct-from-global 3x3 conv GEMM — explicitly software-pipelined.
// Wave = 16 px x 64 co. ALL 18 B-fragments issued up-front (18-deep VMEM
// pipeline); A-fragments ring-4 prefetch distance 3 (L2/L1-hot weights).
// Per-output MFMA order: s ascending — bit-exact vs staged versions.
// ---------------------------------------------------------------------------
static __device__ __forceinline__ void conv3_direct(
    const unsigned short* __restrict__ src,
    const unsigned short* __restrict__ wsrc,
    const unsigned short* __restrict__ zp,
    int b, int h, int w0, int wv, int lane, float4v acc[4])
{
    const int n15  = lane & 15;
    const int quad = lane >> 4;
    const int laneoff = n15 * 64 + quad * 8;           // ushort units
    const unsigned short* zb = zp + laneoff;
    const bool eL = (w0 == 0)  && (wv == 0) && (n15 == 0);    // gw = -1 lane
    const bool eR = (w0 == 64) && (wv == 3) && (n15 == 15);   // gw = 128 lane

    const unsigned short* base[3];
    const unsigned short* baseL[3];
    const unsigned short* baseR[3];
#pragma unroll
    for (int ky = 0; ky < 3; ++ky) {
        const int gh = h - 1 + ky;
        const unsigned short* p = ((unsigned)gh < (unsigned)Hc)
            ? src + (size_t)((b * Hc + gh) * Wc) * 64
                  + (w0 - 1 + wv * 16) * 64 + laneoff
            : zb;
        base[ky]  = p;
        baseL[ky] = eL ? zb : p;
        baseR[ky] = eR ? zb : p;
    }

    // --- issue all 18 B loads (independent, deep pipeline) ---
    short8 bfr[18];
#pragma unroll
    for (int s = 0; s < 18; ++s) {
        const int tap = s >> 1;
        const int sh  = s & 1;
        const int ky  = tap / 3;
        const int kx  = tap % 3;
        const unsigned short* bp =
            (kx == 0) ? baseL[ky] : (kx == 2) ? baseR[ky] : base[ky];
        bfr[s] = *(const short8*)(bp + kx * 64 + sh * 32);
    }

    // --- A ring of 4, prefetch distance 3 ---
    const unsigned short* ap = wsrc + lane * 8;
    short8 afr[4][4];
#pragma unroll
    for (int q = 0; q < 3; ++q)
#pragma unroll
        for (int mt = 0; mt < 4; ++mt)
            afr[q][mt] = *(const short8*)(ap + (size_t)q * 2048 + mt * 512);

#pragma unroll
    for (int s = 0; s < 18; ++s) {
        if (s + 3 < 18) {
#pragma unroll
            for (int mt = 0; mt < 4; ++mt)
                afr[(s + 3) & 3][mt] =
                    *(const short8*)(ap + (size_t)(s + 3) * 2048 + mt * 512);
        }
#pragma unroll
        for (int mt = 0; mt < 4; ++mt)
            acc[mt] = __builtin_amdgcn_mfma_f32_16x16x32_bf16(
                afr[s & 3][mt], bfr[s], acc[mt], 0, 0, 0);
    }
}

// epilogue: bias + optional relu -> bf16 NHWC
#define CONV_EPI_NHWC(ACC, BIASP, OUTP, RELU)                                 \
    {                                                                         \
        const int wpix_ = w0 + wv * 16 + n15;                                 \
        const size_t pb_ = (((size_t)b * Hc + h) * Wc + wpix_) * Cc;          \
        _Pragma("unroll")                                                     \
        for (int mt = 0; mt < 4; ++mt) {                                      \
            const int co0_ = mt * 16 + quad * 4;                              \
            float4 bv_ = *(const float4*)&(BIASP)[co0_];                      \
            float r0 = (ACC)[mt][0] + bv_.x, r1 = (ACC)[mt][1] + bv_.y;       \
            float r2 = (ACC)[mt][2] + bv_.z, r3 = (ACC)[mt][3] + bv_.w;       \
            if (RELU) { r0 = fmaxf(r0, 0.f); r1 = fmaxf(r1, 0.f);             \
                        r2 = fmaxf(r2, 0.f); r3 = fmaxf(r3, 0.f); }           \
            ushort4 pk_;                                                      \
            pk_.x = f2bu(r0); pk_.y = f2bu(r1);                               \
            pk_.z = f2bu(r2); pk_.w = f2bu(r3);                               \
            *(ushort4*)&(OUTP)[pb_ + co0_] = pk_;                             \
        }                                                                     \
    }

// ---------------------------------------------------------------------------
// conv1 (f + m paths, pipelined direct-global) + lp. grid = 2048.
//   slot<128 : conv row tile (h = slot), BOTH tensors.
//   slot>=128: lp blocks (unchanged).
// ---------------------------------------------------------------------------
__global__ __launch_bounds__(256, 2) void conv1_lp_k(
    const unsigned short* __restrict__ xb,
    const unsigned short* __restrict__ kfb,
    const unsigned short* __restrict__ wb1,
    const unsigned short* __restrict__ wb3,
    const float* __restrict__ fb1, const float* __restrict__ mb1,
    const unsigned short* __restrict__ wl1, const float* __restrict__ lb1,
    const unsigned short* __restrict__ wl2, const float* __restrict__ lb2,
    const unsigned short* __restrict__ zpage,
    unsigned short* __restrict__ t1f, unsigned short* __restrict__ t1m,
    unsigned short* __restrict__ lpb)
{
    __shared__ unsigned short s_lp[4 * 1024];

    const int tid  = threadIdx.x;
    const int lane = tid & 63;
    const int wv   = tid >> 6;
    const int quad = lane >> 4;
    const int n15  = lane & 15;
    const int glin = blockIdx.x;
    const int xcd  = glin & 7;
    const int slot = glin >> 3;

    if (slot < 128) {
        const int b  = xcd >> 1;
        const int w0 = (xcd & 1) * 64;
        const int h  = slot;

        float4v acc[4];
#pragma unroll
        for (int mt = 0; mt < 4; ++mt) acc[mt] = (float4v){0.f, 0.f, 0.f, 0.f};
        conv3_direct(xb, wb1, zpage, b, h, w0, wv, lane, acc);
        CONV_EPI_NHWC(acc, fb1, t1f, true);

#pragma unroll
        for (int mt = 0; mt < 4; ++mt) acc[mt] = (float4v){0.f, 0.f, 0.f, 0.f};
        conv3_direct(kfb, wb3, zpage, b, h, w0, wv, lane, acc);
        CONV_EPI_NHWC(acc, mb1, t1m, true);
    } else {
        const int lpid = xcd * 128 + (slot - 128);
        const int p    = lane & 15;
        const size_t pix = (size_t)lpid * 64 + wv * 16 + p;
        unsigned short* st = &s_lp[wv * 1024];

        float4v acc1[4];
#pragma unroll
        for (int mt = 0; mt < 4; ++mt) acc1[mt] = (float4v){0.f, 0.f, 0.f, 0.f};
#pragma unroll
        for (int s = 0; s < 2; ++s) {
            short8 bfr = *(const short8*)&kfb[pix * Cc + s * 32 + quad * 8];
#pragma unroll
            for (int mt = 0; mt < 4; ++mt) {
                short8 afr = *(const short8*)&wl1[(size_t)(((s * 4 + mt) << 6) + lane) << 3];
                acc1[mt] = __builtin_amdgcn_mfma_f32_16x16x32_bf16(afr, bfr, acc1[mt], 0, 0, 0);
            }
        }

#pragma unroll
        for (int mt = 0; mt < 4; ++mt) {
            const int co0 = mt * 16 + quad * 4;
            float4 bv = *(const float4*)&lb1[co0];
            ushort4 pk;
            pk.x = f2bu(fmaxf(acc1[mt][0] + bv.x, 0.f));
            pk.y = f2bu(fmaxf(acc1[mt][1] + bv.y, 0.f));
            pk.z = f2bu(fmaxf(acc1[mt][2] + bv.z, 0.f));
            pk.w = f2bu(fmaxf(acc1[mt][3] + bv.w, 0.f));
            const int cg = co0 >> 3;
            *(ushort4*)&st[p * 64 + ((cg ^ (p & 7)) << 3) + (quad & 1) * 4] = pk;
        }
        __syncthreads();

        float4v acc2[4];
#pragma unroll
        for (int mt = 0; mt < 4; ++mt) acc2[mt] = (float4v){0.f, 0.f, 0.f, 0.f};
#pragma unroll
        for (int s = 0; s < 2; ++s) {
            const int cg = s * 4 + quad;
            short8 bfr = *(const short8*)&st[p * 64 + ((cg ^ (p & 7)) << 3)];
#pragma unroll
            for (int mt = 0; mt < 4; ++mt) {
                short8 afr = *(const short8*)&wl2[(size_t)(((s * 4 + mt) << 6) + lane) << 3];
                acc2[mt] = __builtin_amdgcn_mfma_f32_16x16x32_bf16(afr, bfr, acc2[mt], 0, 0, 0);
            }
        }

        float v[4][4];
        float partial = 0.f;
#pragma unroll
        for (int mt = 0; mt < 4; ++mt) {
#pragma unroll
            for (int r = 0; r < 4; ++r) {
                const int tap = mt * 16 + quad * 4 + r;
                float val = (tap < 49) ? (acc2[mt][r] + lb2[tap]) : 0.f;
                v[mt][r] = val;
                partial += val;
            }
        }
        partial += __shfl_xor(partial, 16, 64);
        partial += __shfl_xor(partial, 32, 64);
        const float m = partial * (1.f / 49.f) - (1.f / 49.f);

        const int bI = (int)(pix >> 14);
        const int hw = (int)(pix & 16383);
#pragma unroll
        for (int mt = 0; mt < 4; ++mt) {
#pragma unroll
            for (int r = 0; r < 4; ++r) {
                const int tap = mt * 16 + quad * 4 + r;
                if (tap < 49)
                    lpb[((size_t)bI * 49 + tap) * HWc + hw] = f2bu(v[mt][r] - m);
            }
        }
    }
}

// ---------------------------------------------------------------------------
// conv2 (f + m, pipelined direct-global), feat = fp*mp -> bf16 NCHW.
// grid = 1024.
// ---------------------------------------------------------------------------
__global__ __launch_bounds__(256, 2) void conv2_fused_k(
    const unsigned short* __restrict__ t1f,
    const unsigned short* __restrict__ t1m,
    const unsigned short* __restrict__ wb2,
    const unsigned short* __restrict__ wb4,
    const float* __restrict__ fb2, const float* __restrict__ mb2,
    const unsigned short* __restrict__ zpage,
    unsigned short* __restrict__ featp)
{
    const int tid  = threadIdx.x;
    const int lane = tid & 63;
    const int wv   = tid >> 6;
    const int quad = lane >> 4;
    const int n15  = lane & 15;
    const int glin = blockIdx.x;
    const int xcd  = glin & 7;
    const int b    = xcd >> 1;
    const int w0   = (xcd & 1) * 64;
    const int h    = glin >> 3;

    float4v acc[4];
#pragma unroll
    for (int mt = 0; mt < 4; ++mt) acc[mt] = (float4v){0.f, 0.f, 0.f, 0.f};
    conv3_direct(t1f, wb2, zpage, b, h, w0, wv, lane, acc);

    float fpv[4][4];
#pragma unroll
    for (int mt = 0; mt < 4; ++mt) {
        const int co0 = mt * 16 + quad * 4;
        float4 bv = *(const float4*)&fb2[co0];
        fpv[mt][0] = bulo((unsigned int)f2bu(acc[mt][0] + bv.x));
        fpv[mt][1] = bulo((unsigned int)f2bu(acc[mt][1] + bv.y));
        fpv[mt][2] = bulo((unsigned int)f2bu(acc[mt][2] + bv.z));
        fpv[mt][3] = bulo((unsigned int)f2bu(acc[mt][3] + bv.w));
    }

#pragma unroll
    for (int mt = 0; mt < 4; ++mt) acc[mt] = (float4v){0.f, 0.f, 0.f, 0.f};
    conv3_direct(t1m, wb4, zpage, b, h, w0, wv, lane, acc);

    const int wpix = w0 + wv * 16 + n15;
    const int px   = h * Wc + wpix;
#pragma unroll
    for (int mt = 0; mt < 4; ++mt) {
        const int co0 = mt * 16 + quad * 4;
        float4 bv = *(const float4*)&mb2[co0];
        float v[4] = {acc[mt][0] + bv.x, acc[mt][1] + bv.y,
                      acc[mt][2] + bv.z, acc[mt][3] + bv.w};
#pragma unroll
        for (int r = 0; r < 4; ++r)
            featp[((size_t)b * Cc + co0 + r) * HWc + px] =
                f2bu(v[r] * fpv[mt][r]);
    }
}

// ---------------------------------------------------------------------------
// Dynamic local 7x7 conv + residual (unchanged).
// ---------------------------------------------------------------------------
__global__ __launch_bounds__(256) void local_conv_v4(
    const float* __restrict__ x, const unsigned short* __restrict__ featp,
    const unsigned short* __restrict__ lp, float* __restrict__ out)
{
    const int tid  = threadIdx.x;
    const int glin = blockIdx.x;
    const int xcd  = glin & 7;
    const int slot = glin >> 3;              // 0..127
    const int pair = xcd * 8 + (slot >> 4);  // 0..63
    const int cg   = slot & 15;
    const int b    = pair >> 4;
    const int hti  = pair & 15;

    const int w4  = (tid & 31) * 4;
    const int ro  = tid >> 5;
    const int h   = hti * 8 + ro;
    const int c0  = cg * 4;

    float msk[12];
#pragma unroll
    for (int e = 0; e < 12; ++e) {
        int gw = w4 - 4 + e;
        msk[e] = ((unsigned)gw < (unsigned)Wc) ? 1.f : 0.f;
    }

    float acc[4][4];
#pragma unroll
    for (int ch = 0; ch < 4; ++ch)
#pragma unroll
        for (int p = 0; p < 4; ++p) acc[ch][p] = 0.f;

    const unsigned short* lpb = lp + (size_t)b * 49 * HWc + (size_t)h * Wc + w4;
    const unsigned short* fb  = featp + ((size_t)b * Cc + c0) * HWc;

#pragma unroll
    for (int dy = 0; dy < 7; ++dy) {
        const int gh = h + dy - 3;
        if ((unsigned)gh >= (unsigned)Hc) continue;

        float lpf[7][4];
#pragma unroll
        for (int dx = 0; dx < 7; ++dx) {
            uint2 lv = *(const uint2*)&lpb[(size_t)(dy * 7 + dx) * HWc];
            lpf[dx][0] = bulo(lv.x); lpf[dx][1] = buhi(lv.x);
            lpf[dx][2] = bulo(lv.y); lpf[dx][3] = buhi(lv.y);
        }

        const unsigned short* frow = fb + (size_t)gh * Wc + w4;
#pragma unroll
        for (int ch = 0; ch < 4; ++ch) {
            const unsigned short* fr = frow + (size_t)ch * HWc;
            uint2 a  = *(const uint2*)(fr - 4);
            uint2 bq = *(const uint2*)(fr);
            uint2 cq = *(const uint2*)(fr + 4);
            float f[12];
            f[0]  = bulo(a.x);             f[1]  = buhi(a.x) * msk[1];
            f[2]  = bulo(a.y) * msk[2];    f[3]  = buhi(a.y) * msk[3];
            f[4]  = bulo(bq.x);            f[5]  = buhi(bq.x);
            f[6]  = bulo(bq.y);            f[7]  = buhi(bq.y);
            f[8]  = bulo(cq.x) * msk[8];   f[9]  = buhi(cq.x) * msk[9];
            f[10] = bulo(cq.y) * msk[10];  f[11] = buhi(cq.y);
#pragma unroll
            for (int dx = 0; dx < 7; ++dx)
#pragma unroll
                for (int p = 0; p < 4; ++p)
                    acc[ch][p] = fmaf(f[p + dx + 1], lpf[dx][p], acc[ch][p]);
        }
    }

#pragma unroll
    for (int ch = 0; ch < 4; ++ch) {
        const size_t idx = ((size_t)b * Cc + c0 + ch) * HWc + (size_t)h * Wc + w4;
        float4 xv = *(const float4*)&x[idx];
        float4 r  = {acc[ch][0] + xv.x, acc[ch][1] + xv.y,
                     acc[ch][2] + xv.z, acc[ch][3] + xv.w};
        *(float4*)&out[idx] = r;
    }
}

// ---------------------------------------------------------------------------
extern "C" void kernel_launch(void* const* d_in, const int* in_sizes, int n_in,
                              void* d_out, int out_size, void* d_ws, size_t ws_size,
                              hipStream_t stream)
{
    const float* x   = (const float*)d_in[0];
    const float* kf  = (const float*)d_in[1];
    const float* fw1 = (const float*)d_in[2];
    const float* fb1 = (const float*)d_in[3];
    const float* fw2 = (const float*)d_in[4];
    const float* fb2 = (const float*)d_in[5];
    const float* mw1 = (const float*)d_in[6];
    const float* mb1 = (const float*)d_in[7];
    const float* mw2 = (const float*)d_in[8];
    const float* mb2 = (const float*)d_in[9];
    const float* lw1 = (const float*)d_in[10];
    const float* lb1 = (const float*)d_in[11];
    const float* lw2 = (const float*)d_in[12];
    const float* lb2 = (const float*)d_in[13];

    float* out = (float*)d_out;
    char*  ws  = (char*)d_ws;

    const size_t NBH = (size_t)Bc * HWc * Cc * 2;   // bf16 tensor: 8.4 MB
    const size_t LPH = (size_t)Bc * 49 * HWc * 2;   // bf16 lp planes: 6.4 MB
    const size_t WBA = (size_t)(4 * 36864 + 2 * 4096) * 2;

    unsigned short* t1f   = (unsigned short*)(ws);
    unsigned short* t1m   = (unsigned short*)(ws + NBH);
    unsigned short* featp = (unsigned short*)(ws + 2 * NBH);
    unsigned short* lpb   = (unsigned short*)(ws + 3 * NBH);
    unsigned short* xb    = (unsigned short*)(ws + 3 * NBH + LPH);
    unsigned short* kfb   = (unsigned short*)((char*)xb + NBH);
    unsigned short* wbase = (unsigned short*)((char*)kfb + NBH);
    unsigned short* zpage = (unsigned short*)((char*)wbase + WBA);
    unsigned short* wb1   = wbase;
    unsigned short* wb2   = wbase + 36864;
    unsigned short* wb3   = wbase + 2 * 36864;
    unsigned short* wb4   = wbase + 3 * 36864;
    unsigned short* wl1   = wbase + 4 * 36864;
    unsigned short* wl2   = wbase + 4 * 36864 + 4096;

    dim3 blk(256);

    prep_k<<<dim3(333), blk, 0, stream>>>(x, kf, fw1, fw2, mw1, mw2, lw1, lw2,
                                          xb, kfb, wbase, zpage);

    conv1_lp_k<<<dim3(2048), blk, 0, stream>>>(xb, kfb, wb1, wb3, fb1, mb1,
                                               wl1, lb1, wl2, lb2, zpage,
                                               t1f, t1m, lpb);

    conv2_fused_k<<<dim3(1024), blk, 0, stream>>>(t1f, t1m, wb2, wb4, fb2, mb2,
                                                  zpage, featp);

    local_conv_v4<<<dim3(1024), blk, 0, stream>>>(x, featp, lpb, out);
}

// Round 6
// 169.545 us; speedup vs baseline: 1.2658x; 1.2658x over previous
//
#include <hip/hip_runtime.h>
#include <hip/hip_bf16.h>

#define Cc 64
#define Hc 128
#define Wc 128
#define HWc (Hc * Wc)
#define Bc 4

typedef __attribute__((ext_vector_type(8))) short short8;
typedef __attribute__((ext_vector_type(4))) float float4v;

static __device__ __forceinline__ unsigned short f2bu(float f) {
    __hip_bfloat16 h = __float2bfloat16(f);
    return *(unsigned short*)&h;
}
static __device__ __forceinline__ float bulo(unsigned int u) {
    return __uint_as_float((u & 0xffffu) << 16);
}
static __device__ __forceinline__ float buhi(unsigned int u) {
    return __uint_as_float(u & 0xffff0000u);
}
static __device__ __forceinline__ unsigned int pk2(float a, float b) {
    return (unsigned int)f2bu(a) | ((unsigned int)f2bu(b) << 16);
}

static __device__ __forceinline__ void gl_lds16(const void* g, void* l) {
    __builtin_amdgcn_global_load_lds(
        (const __attribute__((address_space(1))) unsigned int*)g,
        (__attribute__((address_space(3))) unsigned int*)l, 16, 0, 0);
}

// ---------------------------------------------------------------------------
// prep: blocks 0..255 cvt (float4-vectorized, 4 px/thread),
//       256..327 weight pack (72 blocks), 328..331 lp weights, 332 zpage.
// (round-5 version, correctness-verified)
// ---------------------------------------------------------------------------
__global__ __launch_bounds__(256) void prep_k(
    const float* __restrict__ x, const float* __restrict__ kf,
    const float* __restrict__ fw1, const float* __restrict__ fw2,
    const float* __restrict__ mw1, const float* __restrict__ mw2,
    const float* __restrict__ lw1, const float* __restrict__ lw2,
    unsigned short* __restrict__ xb, unsigned short* __restrict__ kfb,
    unsigned short* __restrict__ wbase, unsigned short* __restrict__ zpage)
{
    const int bid = blockIdx.x;
    const int tid = threadIdx.x;

    if (bid < 256) {
        // gid: [tensor:1][b:2][chalf:1][px4:12]
        const int gid    = bid * 256 + tid;
        const int tensor = gid >> 15;
        const int b      = (gid >> 13) & 3;
        const int chalf  = (gid >> 12) & 1;
        const int px     = (gid & 4095) * 4;
        const bool isx   = (tensor == 0);
        const float* s = (isx ? x : kf) + ((size_t)(b * Cc + chalf * 32)) * HWc + px;
        unsigned short* d = (isx ? xb : kfb) + ((size_t)((size_t)b * HWc + px)) * Cc + chalf * 32;
#pragma unroll
        for (int c8 = 0; c8 < 4; ++c8) {
            unsigned int pk[4][4];   // [px][jp]
#pragma unroll
            for (int jp = 0; jp < 4; ++jp) {
                float4 v0 = *(const float4*)(s + (size_t)(c8 * 8 + jp * 2 + 0) * HWc);
                float4 v1 = *(const float4*)(s + (size_t)(c8 * 8 + jp * 2 + 1) * HWc);
                if (isx) {
                    v0.x = fmaxf(v0.x, 0.f); v0.y = fmaxf(v0.y, 0.f);
                    v0.z = fmaxf(v0.z, 0.f); v0.w = fmaxf(v0.w, 0.f);
                    v1.x = fmaxf(v1.x, 0.f); v1.y = fmaxf(v1.y, 0.f);
                    v1.z = fmaxf(v1.z, 0.f); v1.w = fmaxf(v1.w, 0.f);
                }
                pk[0][jp] = pk2(v0.x, v1.x);
                pk[1][jp] = pk2(v0.y, v1.y);
                pk[2][jp] = pk2(v0.z, v1.z);
                pk[3][jp] = pk2(v0.w, v1.w);
            }
#pragma unroll
            for (int i = 0; i < 4; ++i)
                *(uint4*)(d + (size_t)i * Cc + c8 * 8) =
                    make_uint4(pk[i][0], pk[i][1], pk[i][2], pk[i][3]);
        }
    } else if (bid < 328) {                          // 72 weight-pack blocks
        const int wbid  = bid - 256;
        const int which = wbid / 18;
        const float* w = (which == 0) ? fw1 : (which == 1) ? fw2 : (which == 2) ? mw1 : mw2;
        unsigned short* wb = wbase + (size_t)which * 36864;
        const int g = (wbid % 18) * 256 + tid;
        if (g >= 4608) return;
        const int lane = g & 63;
        const int smt  = g >> 6;
        const int s    = smt >> 2;
        const int mt   = smt & 3;
        const int co   = mt * 16 + (lane & 15);
        const int kb   = s * 32 + (lane >> 4) * 8;
        unsigned int pk[4];
#pragma unroll
        for (int jp = 0; jp < 4; ++jp) {
            int k0 = kb + jp * 2, k1 = k0 + 1;
            float v0 = w[((size_t)co * Cc + (k0 & 63)) * 9 + (k0 >> 6)];
            float v1 = w[((size_t)co * Cc + (k1 & 63)) * 9 + (k1 >> 6)];
            pk[jp] = pk2(v0, v1);
        }
        *(uint4*)(wb + (size_t)g * 8) = make_uint4(pk[0], pk[1], pk[2], pk[3]);
    } else if (bid < 332) {                          // 4 lp-weight blocks
        const int wbid  = bid - 328;
        const int which = wbid >> 1;
        const float* w = which ? lw2 : lw1;
        const int Cout = which ? 49 : 64;
        unsigned short* wb = wbase + 4 * 36864 + (size_t)which * 4096;
        const int g = (wbid & 1) * 256 + tid;
        const int lane = g & 63;
        const int smt  = g >> 6;
        const int s    = smt >> 2;
        const int mt   = smt & 3;
        const int co   = mt * 16 + (lane & 15);
        const int kb   = s * 32 + (lane >> 4) * 8;
        unsigned int pk[4];
#pragma unroll
        for (int jp = 0; jp < 4; ++jp) {
            int k0 = kb + jp * 2, k1 = k0 + 1;
            float v0 = (co < Cout) ? w[(size_t)co * Cc + k0] : 0.f;
            float v1 = (co < Cout) ? w[(size_t)co * Cc + k1] : 0.f;
            pk[jp] = pk2(v0, v1);
        }
        *(uint4*)(wb + (size_t)g * 8) = make_uint4(pk[0], pk[1], pk[2], pk[3]);
    } else {
        uint4 z = make_uint4(0u, 0u, 0u, 0u);
        ((uint4*)zpage)[tid] = z;
        ((uint4*)zpage)[256 + tid] = z;
    }
}

// ===== staging (async DMA, swizzle via lane->channel permutation) ==========
#define STAGE_DMA(INPTR, SBUF)                                                \
    for (int k = wv; k < 33; k += 4) {                                        \
        const int u_  = k * 8 + (lane >> 3);                                  \
        const int j_  = lane & 7;                                             \
        const int r_  = u_ / 66;                                              \
        const int c_  = u_ - r_ * 66;                                         \
        const int gh_ = h0 - 1 + r_;                                          \
        const int gw_ = w0 - 1 + c_;                                          \
        const bool ok_ = ((unsigned)gh_ < (unsigned)Hc) && ((unsigned)gw_ < (unsigned)Wc); \
        const int ch_ = j_ ^ (u_ & 7);                                        \
        const unsigned short* g_ = ok_                                        \
            ? (INPTR) + ((((size_t)b * Hc + gh_) * Wc + gw_) << 6) + (ch_ << 3) \
            : zpage + (ch_ << 3);                                             \
        gl_lds16(g_, &(SBUF)[k * 512]);                                       \
    }

#define LOAD_A(W, s, m) (*(const short8*)((W) + (size_t)(s) * 2048 + (size_t)(m) * 512))
#define LOAD_B(SB, s, nt) ({                                                  \
        const int tap_ = (s) >> 1;                                            \
        const int qb_  = rowb[tap_ / 3] + tap_ % 3;                           \
        const int ch0_ = ((s) & 1) * 4 + quad;                                \
        *(const short8*)&(SB)[(qb_ + (nt) * 16) * 64 + ((ch0_ ^ (qb_ & 7)) << 3)]; })

// Software-pipelined GEMM. A: ring of 4, prefetch distance 3.
// B: explicit depth-1 cur/nxt.  (round-0, proven)
#define CONV_GEMM(APTR, ACC, SB)                                              \
    {                                                                         \
        short8 a_buf[4][2], b_cur[4], b_nxt[4];                               \
        _Pragma("unroll")                                                     \
        for (int q = 0; q < 3; ++q)                                           \
            _Pragma("unroll")                                                 \
            for (int m = 0; m < 2; ++m) a_buf[q][m] = LOAD_A(APTR, q, m);     \
        _Pragma("unroll")                                                     \
        for (int nt = 0; nt < 4; ++nt) b_cur[nt] = LOAD_B(SB, 0, nt);         \
        _Pragma("unroll")                                                     \
        for (int s = 0; s < 18; ++s) {                                        \
            if (s + 3 < 18) {                                                 \
                _Pragma("unroll")                                             \
                for (int m = 0; m < 2; ++m)                                   \
                    a_buf[(s + 3) & 3][m] = LOAD_A(APTR, s + 3, m);           \
            }                                                                 \
            if (s + 1 < 18) {                                                 \
                _Pragma("unroll")                                             \
                for (int nt = 0; nt < 4; ++nt)                                \
                    b_nxt[nt] = LOAD_B(SB, s + 1, nt);                        \
            }                                                                 \
            _Pragma("unroll")                                                 \
            for (int nt = 0; nt < 4; ++nt)                                    \
                _Pragma("unroll")                                             \
                for (int m = 0; m < 2; ++m)                                   \
                    ACC[m][nt] = __builtin_amdgcn_mfma_f32_16x16x32_bf16(     \
                        a_buf[s & 3][m], b_cur[nt], ACC[m][nt], 0, 0, 0);     \
            if (s + 1 < 18) {                                                 \
                _Pragma("unroll")                                             \
                for (int nt = 0; nt < 4; ++nt) b_cur[nt] = b_nxt[nt];         \
            }                                                                 \
        }                                                                     \
    }

// ---------------------------------------------------------------------------
// conv1 + lp folded into m-blocks. grid = 1024.
//   slot 0..127: sel = slot>>6 picks tensor (0:f, 1:m), hti = slot&63,
//   2-row tile.  m-blocks additionally compute lp for their 2 row-groups
//   (round-1-proven folded code path, kfb read from global).
// ---------------------------------------------------------------------------
__global__ __launch_bounds__(256) void conv1_lp_k(
    const unsigned short* __restrict__ in0,
    const unsigned short* __restrict__ in1,
    const unsigned short* __restrict__ wfrag0,
    const unsigned short* __restrict__ wfrag1,
    const float* __restrict__ bias0,
    const float* __restrict__ bias1,
    const unsigned short* __restrict__ zpage,
    unsigned short* __restrict__ out0,
    unsigned short* __restrict__ out1,
    const unsigned short* __restrict__ w1, const float* __restrict__ b1,
    const unsigned short* __restrict__ w2, const float* __restrict__ b2,
    unsigned short* __restrict__ lpout)
{
    __shared__ unsigned short s_b[264 * 64];

    const int tid  = threadIdx.x;
    const int lane = tid & 63;
    const int wv   = tid >> 6;
    const int quad = lane >> 4;
    const int glin = blockIdx.x;
    const int xcd  = glin & 7;
    const int slot = glin >> 3;          // 0..127

    const int sel = slot >> 6;
    const int hti = slot & 63;
    const int b   = xcd >> 1;
    const int w0  = (xcd & 1) * 64;
    const int h0  = hti * 2;

    const unsigned short* in    = sel ? in1 : in0;
    const unsigned short* wfrag = sel ? wfrag1 : wfrag0;
    const float*          bias  = sel ? bias1 : bias0;
    unsigned short*       out   = sel ? out1 : out0;

    STAGE_DMA(in, s_b);
    __syncthreads();

    const int rowsel = wv >> 1;
    const int cohalf = wv & 1;
    const int n15    = lane & 15;
    const unsigned short* aptr = wfrag + (((size_t)(cohalf * 2) * 64 + lane) << 3);

    int rowb[3];
#pragma unroll
    for (int ky = 0; ky < 3; ++ky) rowb[ky] = (rowsel + ky) * 66 + n15;

    float4v acc[2][4];
#pragma unroll
    for (int m = 0; m < 2; ++m)
#pragma unroll
        for (int nt = 0; nt < 4; ++nt) acc[m][nt] = (float4v){0.f, 0.f, 0.f, 0.f};

    CONV_GEMM(aptr, acc, s_b);

    const int h = h0 + rowsel;
#pragma unroll
    for (int m = 0; m < 2; ++m) {
        const int mt  = cohalf * 2 + m;
        const int co0 = mt * 16 + quad * 4;
        float4 bv = *(const float4*)&bias[co0];
#pragma unroll
        for (int nt = 0; nt < 4; ++nt) {
            const size_t pix = ((size_t)b * Hc + h) * Wc + w0 + nt * 16 + n15;
            ushort4 pk;
            pk.x = f2bu(fmaxf(acc[m][nt][0] + bv.x, 0.f));
            pk.y = f2bu(fmaxf(acc[m][nt][1] + bv.y, 0.f));
            pk.z = f2bu(fmaxf(acc[m][nt][2] + bv.z, 0.f));
            pk.w = f2bu(fmaxf(acc[m][nt][3] + bv.w, 0.f));
            *(ushort4*)&out[pix * Cc + co0] = pk;
        }
    }

    if (sel == 1) {
        __syncthreads();   // conv LDS reads done before lp reuses s_b

        const int p = lane & 15;
#pragma unroll 1
        for (int ui = 0; ui < 2; ++ui) {
            const int hl = h0 + ui;
            const size_t pix = ((size_t)b * Hc + hl) * Wc + w0 + wv * 16 + p;
            unsigned short* st = &s_b[(size_t)(ui * 4 + wv) * 1024];

            float4v acc1[4];
#pragma unroll
            for (int mt = 0; mt < 4; ++mt) acc1[mt] = (float4v){0.f, 0.f, 0.f, 0.f};
#pragma unroll
            for (int s = 0; s < 2; ++s) {
                short8 bfr = *(const short8*)&in1[pix * Cc + s * 32 + quad * 8];
#pragma unroll
                for (int mt = 0; mt < 4; ++mt) {
                    short8 afr = *(const short8*)&w1[(size_t)(((s * 4 + mt) << 6) + lane) << 3];
                    acc1[mt] = __builtin_amdgcn_mfma_f32_16x16x32_bf16(afr, bfr, acc1[mt], 0, 0, 0);
                }
            }

#pragma unroll
            for (int mt = 0; mt < 4; ++mt) {
                const int co0 = mt * 16 + quad * 4;
                float4 bv = *(const float4*)&b1[co0];
                ushort4 pk;
                pk.x = f2bu(fmaxf(acc1[mt][0] + bv.x, 0.f));
                pk.y = f2bu(fmaxf(acc1[mt][1] + bv.y, 0.f));
                pk.z = f2bu(fmaxf(acc1[mt][2] + bv.z, 0.f));
                pk.w = f2bu(fmaxf(acc1[mt][3] + bv.w, 0.f));
                const int cg = co0 >> 3;
                *(ushort4*)&st[p * 64 + ((cg ^ (p & 7)) << 3) + (quad & 1) * 4] = pk;
            }
            __syncthreads();

            float4v acc2[4];
#pragma unroll
            for (int mt = 0; mt < 4; ++mt) acc2[mt] = (float4v){0.f, 0.f, 0.f, 0.f};
#pragma unroll
            for (int s = 0; s < 2; ++s) {
                const int cg = s * 4 + quad;
                short8 bfr = *(const short8*)&st[p * 64 + ((cg ^ (p & 7)) << 3)];
#pragma unroll
                for (int mt = 0; mt < 4; ++mt) {
                    short8 afr = *(const short8*)&w2[(size_t)(((s * 4 + mt) << 6) + lane) << 3];
                    acc2[mt] = __builtin_amdgcn_mfma_f32_16x16x32_bf16(afr, bfr, acc2[mt], 0, 0, 0);
                }
            }

            float v[4][4];
            float partial = 0.f;
#pragma unroll
            for (int mt = 0; mt < 4; ++mt) {
#pragma unroll
                for (int r = 0; r < 4; ++r) {
                    const int tap = mt * 16 + quad * 4 + r;
                    float val = (tap < 49) ? (acc2[mt][r] + b2[tap]) : 0.f;
                    v[mt][r] = val;
                    partial += val;
                }
            }
            partial += __shfl_xor(partial, 16, 64);
            partial += __shfl_xor(partial, 32, 64);
            const float m = partial * (1.f / 49.f) - (1.f / 49.f);

            const int bI = (int)(pix >> 14);
            const int hw = (int)(pix & 16383);
#pragma unroll
            for (int mt = 0; mt < 4; ++mt) {
#pragma unroll
                for (int r = 0; r < 4; ++r) {
                    const int tap = mt * 16 + quad * 4 + r;
                    if (tap < 49)
                        lpout[((size_t)bI * 49 + tap) * HWc + hw] = f2bu(v[mt][r] - m);
                }
            }
        }
    }
}

// ---------------------------------------------------------------------------
// conv2 fused (round-0, unchanged): BOTH tiles DMA'd up-front into double
// LDS, ONE barrier, two GEMMs, feat = fp*mp -> bf16 NCHW. grid = 512.
// ---------------------------------------------------------------------------
__global__ __launch_bounds__(256) void conv2_fused_k(
    const unsigned short* __restrict__ t1f,
    const unsigned short* __restrict__ t1m,
    const unsigned short* __restrict__ wf,
    const unsigned short* __restrict__ wm,
    const float* __restrict__ bf,
    const float* __restrict__ bm,
    const unsigned short* __restrict__ zpage,
    unsigned short* __restrict__ featp)
{
    __shared__ unsigned short s_b2[2][264 * 64];

    const int tid  = threadIdx.x;
    const int lane = tid & 63;
    const int wv   = tid >> 6;
    const int glin = blockIdx.x;
    const int xcd  = glin & 7;
    const int slot = glin >> 3;          // 0..63
    const int b    = xcd >> 1;
    const int w0   = (xcd & 1) * 64;
    const int h0   = slot * 2;

    STAGE_DMA(t1f, s_b2[0]);
    STAGE_DMA(t1m, s_b2[1]);
    __syncthreads();

    const int rowsel = wv >> 1;
    const int cohalf = wv & 1;
    const int quad   = lane >> 4;
    const int n15    = lane & 15;

    int rowb[3];
#pragma unroll
    for (int ky = 0; ky < 3; ++ky) rowb[ky] = (rowsel + ky) * 66 + n15;

    float4v acc[2][4];
#pragma unroll
    for (int m = 0; m < 2; ++m)
#pragma unroll
        for (int nt = 0; nt < 4; ++nt) acc[m][nt] = (float4v){0.f, 0.f, 0.f, 0.f};

    {
        const unsigned short* aptr = wf + (((size_t)(cohalf * 2) * 64 + lane) << 3);
        CONV_GEMM(aptr, acc, s_b2[0]);
    }

    float fpv[2][4][4];
#pragma unroll
    for (int m = 0; m < 2; ++m) {
        const int mt  = cohalf * 2 + m;
        const int co0 = mt * 16 + quad * 4;
        float4 bv = *(const float4*)&bf[co0];
#pragma unroll
        for (int nt = 0; nt < 4; ++nt) {
            fpv[m][nt][0] = bulo((unsigned int)f2bu(acc[m][nt][0] + bv.x));
            fpv[m][nt][1] = bulo((unsigned int)f2bu(acc[m][nt][1] + bv.y));
            fpv[m][nt][2] = bulo((unsigned int)f2bu(acc[m][nt][2] + bv.z));
            fpv[m][nt][3] = bulo((unsigned int)f2bu(acc[m][nt][3] + bv.w));
        }
    }

#pragma unroll
    for (int m = 0; m < 2; ++m)
#pragma unroll
        for (int nt = 0; nt < 4; ++nt) acc[m][nt] = (float4v){0.f, 0.f, 0.f, 0.f};

    {
        const unsigned short* aptr = wm + (((size_t)(cohalf * 2) * 64 + lane) << 3);
        CONV_GEMM(aptr, acc, s_b2[1]);
    }

    const int h = h0 + rowsel;
#pragma unroll
    for (int m = 0; m < 2; ++m) {
        const int mt  = cohalf * 2 + m;
        const int co0 = mt * 16 + quad * 4;
        float4 bv = *(const float4*)&bm[co0];
#pragma unroll
        for (int nt = 0; nt < 4; ++nt) {
            const int px = h * Wc + w0 + nt * 16 + n15;
            float v[4] = {acc[m][nt][0] + bv.x, acc[m][nt][1] + bv.y,
                          acc[m][nt][2] + bv.z, acc[m][nt][3] + bv.w};
#pragma unroll
            for (int r = 0; r < 4; ++r)
                featp[((size_t)b * Cc + co0 + r) * HWc + px] =
                    f2bu(v[r] * fpv[m][nt][r]);
        }
    }
}

// ---------------------------------------------------------------------------
// Dynamic local 7x7 conv + residual (round-0, unchanged).
// ---------------------------------------------------------------------------
__global__ __launch_bounds__(256) void local_conv_v4(
    const float* __restrict__ x, const unsigned short* __restrict__ featp,
    const unsigned short* __restrict__ lp, float* __restrict__ out)
{
    const int tid  = threadIdx.x;
    const int glin = blockIdx.x;
    const int xcd  = glin & 7;
    const int slot = glin >> 3;              // 0..127
    const int pair = xcd * 8 + (slot >> 4);  // 0..63
    const int cg   = slot & 15;
    const int b    = pair >> 4;
    const int hti  = pair & 15;

    const int w4  = (tid & 31) * 4;
    const int ro  = tid >> 5;
    const int h   = hti * 8 + ro;
    const int c0  = cg * 4;

    float msk[12];
#pragma unroll
    for (int e = 0; e < 12; ++e) {
        int gw = w4 - 4 + e;
        msk[e] = ((unsigned)gw < (unsigned)Wc) ? 1.f : 0.f;
    }

    float acc[4][4];
#pragma unroll
    for (int ch = 0; ch < 4; ++ch)
#pragma unroll
        for (int p = 0; p < 4; ++p) acc[ch][p] = 0.f;

    const unsigned short* lpb = lp + (size_t)b * 49 * HWc + (size_t)h * Wc + w4;
    const unsigned short* fb  = featp + ((size_t)b * Cc + c0) * HWc;

#pragma unroll
    for (int dy = 0; dy < 7; ++dy) {
        const int gh = h + dy - 3;
        if ((unsigned)gh >= (unsigned)Hc) continue;

        float lpf[7][4];
#pragma unroll
        for (int dx = 0; dx < 7; ++dx) {
            uint2 lv = *(const uint2*)&lpb[(size_t)(dy * 7 + dx) * HWc];
            lpf[dx][0] = bulo(lv.x); lpf[dx][1] = buhi(lv.x);
            lpf[dx][2] = bulo(lv.y); lpf[dx][3] = buhi(lv.y);
        }

        const unsigned short* frow = fb + (size_t)gh * Wc + w4;
#pragma unroll
        for (int ch = 0; ch < 4; ++ch) {
            const unsigned short* fr = frow + (size_t)ch * HWc;
            uint2 a  = *(const uint2*)(fr - 4);
            uint2 bq = *(const uint2*)(fr);
            uint2 cq = *(const uint2*)(fr + 4);
            float f[12];
            f[0]  = bulo(a.x);             f[1]  = buhi(a.x) * msk[1];
            f[2]  = bulo(a.y) * msk[2];    f[3]  = buhi(a.y) * msk[3];
            f[4]  = bulo(bq.x);            f[5]  = buhi(bq.x);
            f[6]  = bulo(bq.y);            f[7]  = buhi(bq.y);
            f[8]  = bulo(cq.x) * msk[8];   f[9]  = buhi(cq.x) * msk[9];
            f[10] = bulo(cq.y) * msk[10];  f[11] = buhi(cq.y);
#pragma unroll
            for (int dx = 0; dx < 7; ++dx)
#pragma unroll
                for (int p = 0; p < 4; ++p)
                    acc[ch][p] = fmaf(f[p + dx + 1], lpf[dx][p], acc[ch][p]);
        }
    }

#pragma unroll
    for (int ch = 0; ch < 4; ++ch) {
        const size_t idx = ((size_t)b * Cc + c0 + ch) * HWc + (size_t)h * Wc + w4;
        float4 xv = *(const float4*)&x[idx];
        float4 r  = {acc[ch][0] + xv.x, acc[ch][1] + xv.y,
                     acc[ch][2] + xv.z, acc[ch][3] + xv.w};
        *(float4*)&out[idx] = r;
    }
}

// ---------------------------------------------------------------------------
extern "C" void kernel_launch(void* const* d_in, const int* in_sizes, int n_in,
                              void* d_out, int out_size, void* d_ws, size_t ws_size,
                              hipStream_t stream)
{
    const float* x   = (const float*)d_in[0];
    const float* kf  = (const float*)d_in[1];
    const float* fw1 = (const float*)d_in[2];
    const float* fb1 = (const float*)d_in[3];
    const float* fw2 = (const float*)d_in[4];
    const float* fb2 = (const float*)d_in[5];
    const float* mw1 = (const float*)d_in[6];
    const float* mb1 = (const float*)d_in[7];
    const float* mw2 = (const float*)d_in[8];
    const float* mb2 = (const float*)d_in[9];
    const float* lw1 = (const float*)d_in[10];
    const float* lb1 = (const float*)d_in[11];
    const float* lw2 = (const float*)d_in[12];
    const float* lb2 = (const float*)d_in[13];

    float* out = (float*)d_out;
    char*  ws  = (char*)d_ws;

    const size_t NBH = (size_t)Bc * HWc * Cc * 2;   // bf16 tensor: 8.4 MB
    const size_t LPH = (size_t)Bc * 49 * HWc * 2;   // bf16 lp planes: 6.4 MB
    const size_t WBA = (size_t)(4 * 36864 + 2 * 4096) * 2;

    unsigned short* t1f   = (unsigned short*)(ws);
    unsigned short* t1m   = (unsigned short*)(ws + NBH);
    unsigned short* featp = (unsigned short*)(ws + 2 * NBH);
    unsigned short* lpb   = (unsigned short*)(ws + 3 * NBH);
    unsigned short* xb    = (unsigned short*)(ws + 3 * NBH + LPH);
    unsigned short* kfb   = (unsigned short*)((char*)xb + NBH);
    unsigned short* wbase = (unsigned short*)((char*)kfb + NBH);
    unsigned short* zpage = (unsigned short*)((char*)wbase + WBA);
    unsigned short* wb1   = wbase;
    unsigned short* wb2   = wbase + 36864;
    unsigned short* wb3   = wbase + 2 * 36864;
    unsigned short* wb4   = wbase + 3 * 36864;
    unsigned short* wl1   = wbase + 4 * 36864;
    unsigned short* wl2   = wbase + 4 * 36864 + 4096;

    dim3 blk(256);

    prep_k<<<dim3(333), blk, 0, stream>>>(x, kf, fw1, fw2, mw1, mw2, lw1, lw2,
                                          xb, kfb, wbase, zpage);

    conv1_lp_k<<<dim3(1024), blk, 0, stream>>>(xb, kfb, wb1, wb3, fb1, mb1, zpage,
                                               t1f, t1m, wl1, lb1, wl2, lb2, lpb);

    conv2_fused_k<<<dim3(512), blk, 0, stream>>>(t1f, t1m, wb2, wb4, fb2, mb2,
                                                 zpage, featp);

    local_conv_v4<<<dim3(1024), blk, 0, stream>>>(x, featp, lpb, out);
}

// Round 7
// 161.864 us; speedup vs baseline: 1.3259x; 1.0475x over previous
//
#include <hip/hip_runtime.h>
#include <hip/hip_bf16.h>

#define Cc 64
#define Hc 128
#define Wc 128
#define HWc (Hc * Wc)
#define Bc 4

typedef __attribute__((ext_vector_type(8))) short short8;
typedef __attribute__((ext_vector_type(4))) float float4v;

static __device__ __forceinline__ unsigned short f2bu(float f) {
    __hip_bfloat16 h = __float2bfloat16(f);
    return *(unsigned short*)&h;
}
static __device__ __forceinline__ float bulo(unsigned int u) {
    return __uint_as_float((u & 0xffffu) << 16);
}
static __device__ __forceinline__ float buhi(unsigned int u) {
    return __uint_as_float(u & 0xffff0000u);
}

static __device__ __forceinline__ void gl_lds16(const void* g, void* l) {
    __builtin_amdgcn_global_load_lds(
        (const __attribute__((address_space(1))) unsigned int*)g,
        (__attribute__((address_space(3))) unsigned int*)l, 16, 0, 0);
}

// ---------------------------------------------------------------------------
// prep: blocks 0..511 cvt, 512..587 weight pack, 588 zpage zero.
// ---------------------------------------------------------------------------
__global__ __launch_bounds__(256) void prep_k(
    const float* __restrict__ x, const float* __restrict__ kf,
    const float* __restrict__ fw1, const float* __restrict__ fw2,
    const float* __restrict__ mw1, const float* __restrict__ mw2,
    const float* __restrict__ lw1, const float* __restrict__ lw2,
    unsigned short* __restrict__ xb, unsigned short* __restrict__ kfb,
    unsigned short* __restrict__ wbase, unsigned short* __restrict__ zpage)
{
    const int bid = blockIdx.x;
    const int tid = threadIdx.x;

    if (bid < 512) {
        const bool isx = bid < 256;
        const float* src = isx ? x : kf;
        unsigned short* dst = isx ? xb : kfb;
        const int px = (isx ? bid : bid - 256) * 256 + tid;
        const int b  = px >> 14;
        const int hw = px & 16383;
        const float* s = src + (size_t)b * Cc * HWc + hw;
        unsigned short* d = dst + (size_t)px * Cc;
#pragma unroll
        for (int c8 = 0; c8 < 8; ++c8) {
            unsigned int pk[4];
#pragma unroll
            for (int jp = 0; jp < 4; ++jp) {
                float v0 = s[(size_t)(c8 * 8 + jp * 2 + 0) * HWc];
                float v1 = s[(size_t)(c8 * 8 + jp * 2 + 1) * HWc];
                if (isx) { v0 = fmaxf(v0, 0.f); v1 = fmaxf(v1, 0.f); }
                pk[jp] = (unsigned int)f2bu(v0) | ((unsigned int)f2bu(v1) << 16);
            }
            *(uint4*)(d + c8 * 8) = make_uint4(pk[0], pk[1], pk[2], pk[3]);
        }
    } else if (bid < 584) {
        const int wbid  = bid - 512;
        const int which = wbid / 18;
        const float* w = (which == 0) ? fw1 : (which == 1) ? fw2 : (which == 2) ? mw1 : mw2;
        unsigned short* wb = wbase + (size_t)which * 36864;
        const int g = (wbid % 18) * 256 + tid;
        if (g >= 4608) return;
        const int lane = g & 63;
        const int smt  = g >> 6;
        const int s    = smt >> 2;
        const int mt   = smt & 3;
        const int co   = mt * 16 + (lane & 15);
        const int kb   = s * 32 + (lane >> 4) * 8;
        unsigned int pk[4];
#pragma unroll
        for (int jp = 0; jp < 4; ++jp) {
            int k0 = kb + jp * 2, k1 = k0 + 1;
            float v0 = w[((size_t)co * Cc + (k0 & 63)) * 9 + (k0 >> 6)];
            float v1 = w[((size_t)co * Cc + (k1 & 63)) * 9 + (k1 >> 6)];
            pk[jp] = (unsigned int)f2bu(v0) | ((unsigned int)f2bu(v1) << 16);
        }
        *(uint4*)(wb + (size_t)g * 8) = make_uint4(pk[0], pk[1], pk[2], pk[3]);
    } else if (bid < 588) {
        const int wbid  = bid - 584;
        const int which = wbid >> 1;
        const float* w = which ? lw2 : lw1;
        const int Cout = which ? 49 : 64;
        unsigned short* wb = wbase + 4 * 36864 + (size_t)which * 4096;
        const int g = (wbid & 1) * 256 + tid;
        const int lane = g & 63;
        const int smt  = g >> 6;
        const int s    = smt >> 2;
        const int mt   = smt & 3;
        const int co   = mt * 16 + (lane & 15);
        const int kb   = s * 32 + (lane >> 4) * 8;
        unsigned int pk[4];
#pragma unroll
        for (int jp = 0; jp < 4; ++jp) {
            int k0 = kb + jp * 2, k1 = k0 + 1;
            float v0 = (co < Cout) ? w[(size_t)co * Cc + k0] : 0.f;
            float v1 = (co < Cout) ? w[(size_t)co * Cc + k1] : 0.f;
            pk[jp] = (unsigned int)f2bu(v0) | ((unsigned int)f2bu(v1) << 16);
        }
        *(uint4*)(wb + (size_t)g * 8) = make_uint4(pk[0], pk[1], pk[2], pk[3]);
    } else {
        if (tid < 64) ((unsigned int*)zpage)[tid] = 0;
    }
}

// ===== staging (async DMA, swizzle via lane->channel permutation) ==========
#define STAGE_DMA(INPTR, SBUF)                                                \
    for (int k = wv; k < 33; k += 4) {                                        \
        const int u_  = k * 8 + (lane >> 3);                                  \
        const int j_  = lane & 7;                                             \
        const int r_  = u_ / 66;                                              \
        const int c_  = u_ - r_ * 66;                                         \
        const int gh_ = h0 - 1 + r_;                                          \
        const int gw_ = w0 - 1 + c_;                                          \
        const bool ok_ = ((unsigned)gh_ < (unsigned)Hc) && ((unsigned)gw_ < (unsigned)Wc); \
        const int ch_ = j_ ^ (u_ & 7);                                        \
        const unsigned short* g_ = ok_                                        \
            ? (INPTR) + ((((size_t)b * Hc + gh_) * Wc + gw_) << 6) + (ch_ << 3) \
            : zpage + (ch_ << 3);                                             \
        gl_lds16(g_, &(SBUF)[k * 512]);                                       \
    }

#define LOAD_A(W, s, m) (*(const short8*)((W) + (size_t)(s) * 2048 + (size_t)(m) * 512))
#define LOAD_B(SB, s, nt) ({                                                  \
        const int tap_ = (s) >> 1;                                            \
        const int qb_  = rowb[tap_ / 3] + tap_ % 3;                           \
        const int ch0_ = ((s) & 1) * 4 + quad;                                \
        *(const short8*)&(SB)[(qb_ + (nt) * 16) * 64 + ((ch0_ ^ (qb_ & 7)) << 3)]; })

// Software-pipelined GEMM. A: ring of 4, prefetch distance 3.
// B: explicit depth-1 cur/nxt.
#define CONV_GEMM(APTR, ACC, SB)                                              \
    {                                                                         \
        short8 a_buf[4][2], b_cur[4], b_nxt[4];                               \
        _Pragma("unroll")                                                     \
        for (int q = 0; q < 3; ++q)                                           \
            _Pragma("unroll")                                                 \
            for (int m = 0; m < 2; ++m) a_buf[q][m] = LOAD_A(APTR, q, m);     \
        _Pragma("unroll")                                                     \
        for (int nt = 0; nt < 4; ++nt) b_cur[nt] = LOAD_B(SB, 0, nt);         \
        _Pragma("unroll")                                                     \
        for (int s = 0; s < 18; ++s) {                                        \
            if (s + 3 < 18) {                                                 \
                _Pragma("unroll")                                             \
                for (int m = 0; m < 2; ++m)                                   \
                    a_buf[(s + 3) & 3][m] = LOAD_A(APTR, s + 3, m);           \
            }                                                                 \
            if (s + 1 < 18) {                                                 \
                _Pragma("unroll")                                             \
                for (int nt = 0; nt < 4; ++nt)                                \
                    b_nxt[nt] = LOAD_B(SB, s + 1, nt);                        \
            }                                                                 \
            _Pragma("unroll")                                                 \
            for (int nt = 0; nt < 4; ++nt)                                    \
                _Pragma("unroll")                                             \
                for (int m = 0; m < 2; ++m)                                   \
                    ACC[m][nt] = __builtin_amdgcn_mfma_f32_16x16x32_bf16(     \
                        a_buf[s & 3][m], b_cur[nt], ACC[m][nt], 0, 0, 0);     \
            if (s + 1 < 18) {                                                 \
                _Pragma("unroll")                                             \
                for (int nt = 0; nt < 4; ++nt) b_cur[nt] = b_nxt[nt];         \
            }                                                                 \
        }                                                                     \
    }

// ---------------------------------------------------------------------------
// conv1 + lp merged, 2-row tiles, producer-aligned XCD map (round-0 best).
// ---------------------------------------------------------------------------
__global__ __launch_bounds__(256) void conv1_lp_k(
    const unsigned short* __restrict__ in0,
    const unsigned short* __restrict__ in1,
    const unsigned short* __restrict__ wfrag0,
    const unsigned short* __restrict__ wfrag1,
    const float* __restrict__ bias0,
    const float* __restrict__ bias1,
    const unsigned short* __restrict__ zpage,
    unsigned short* __restrict__ out0,
    unsigned short* __restrict__ out1,
    const unsigned short* __restrict__ w1, const float* __restrict__ b1,
    const unsigned short* __restrict__ w2, const float* __restrict__ b2,
    unsigned short* __restrict__ lpout)
{
    __shared__ unsigned short s_b[264 * 64];

    const int tid  = threadIdx.x;
    const int lane = tid & 63;
    const int wv   = tid >> 6;
    const int quad = lane >> 4;
    const int glin = blockIdx.x;
    const int xcd  = glin & 7;
    const int slot = glin >> 3;

    if (slot < 128) {
        const int sel = slot >> 6;
        const int hti = slot & 63;
        const int b   = xcd >> 1;
        const int w0  = (xcd & 1) * 64;
        const int h0  = hti * 2;

        const unsigned short* in    = sel ? in1 : in0;
        const unsigned short* wfrag = sel ? wfrag1 : wfrag0;
        const float*          bias  = sel ? bias1 : bias0;
        unsigned short*       out   = sel ? out1 : out0;

        STAGE_DMA(in, s_b);
        __syncthreads();

        const int rowsel = wv >> 1;
        const int cohalf = wv & 1;
        const int n15    = lane & 15;
        const unsigned short* aptr = wfrag + (((size_t)(cohalf * 2) * 64 + lane) << 3);

        int rowb[3];
#pragma unroll
        for (int ky = 0; ky < 3; ++ky) rowb[ky] = (rowsel + ky) * 66 + n15;

        float4v acc[2][4];
#pragma unroll
        for (int m = 0; m < 2; ++m)
#pragma unroll
            for (int nt = 0; nt < 4; ++nt) acc[m][nt] = (float4v){0.f, 0.f, 0.f, 0.f};

        CONV_GEMM(aptr, acc, s_b);

        const int h = h0 + rowsel;
#pragma unroll
        for (int m = 0; m < 2; ++m) {
            const int mt  = cohalf * 2 + m;
            const int co0 = mt * 16 + quad * 4;
            float4 bv = *(const float4*)&bias[co0];
#pragma unroll
            for (int nt = 0; nt < 4; ++nt) {
                const size_t pix = ((size_t)b * Hc + h) * Wc + w0 + nt * 16 + n15;
                ushort4 pk;
                pk.x = f2bu(fmaxf(acc[m][nt][0] + bv.x, 0.f));
                pk.y = f2bu(fmaxf(acc[m][nt][1] + bv.y, 0.f));
                pk.z = f2bu(fmaxf(acc[m][nt][2] + bv.z, 0.f));
                pk.w = f2bu(fmaxf(acc[m][nt][3] + bv.w, 0.f));
                *(ushort4*)&out[pix * Cc + co0] = pk;
            }
        }
    } else {
        const int lpid = xcd * 128 + (slot - 128);
        const int p    = lane & 15;
        const size_t pix = (size_t)lpid * 64 + wv * 16 + p;
        unsigned short* st = &s_b[wv * 1024];

        float4v acc1[4];
#pragma unroll
        for (int mt = 0; mt < 4; ++mt) acc1[mt] = (float4v){0.f, 0.f, 0.f, 0.f};
#pragma unroll
        for (int s = 0; s < 2; ++s) {
            short8 bfr = *(const short8*)&in1[pix * Cc + s * 32 + quad * 8];
#pragma unroll
            for (int mt = 0; mt < 4; ++mt) {
                short8 afr = *(const short8*)&w1[(size_t)(((s * 4 + mt) << 6) + lane) << 3];
                acc1[mt] = __builtin_amdgcn_mfma_f32_16x16x32_bf16(afr, bfr, acc1[mt], 0, 0, 0);
            }
        }

#pragma unroll
        for (int mt = 0; mt < 4; ++mt) {
            const int co0 = mt * 16 + quad * 4;
            float4 bv = *(const float4*)&b1[co0];
            ushort4 pk;
            pk.x = f2bu(fmaxf(acc1[mt][0] + bv.x, 0.f));
            pk.y = f2bu(fmaxf(acc1[mt][1] + bv.y, 0.f));
            pk.z = f2bu(fmaxf(acc1[mt][2] + bv.z, 0.f));
            pk.w = f2bu(fmaxf(acc1[mt][3] + bv.w, 0.f));
            const int cg = co0 >> 3;
            *(ushort4*)&st[p * 64 + ((cg ^ (p & 7)) << 3) + (quad & 1) * 4] = pk;
        }
        __syncthreads();

        float4v acc2[4];
#pragma unroll
        for (int mt = 0; mt < 4; ++mt) acc2[mt] = (float4v){0.f, 0.f, 0.f, 0.f};
#pragma unroll
        for (int s = 0; s < 2; ++s) {
            const int cg = s * 4 + quad;
            short8 bfr = *(const short8*)&st[p * 64 + ((cg ^ (p & 7)) << 3)];
#pragma unroll
            for (int mt = 0; mt < 4; ++mt) {
                short8 afr = *(const short8*)&w2[(size_t)(((s * 4 + mt) << 6) + lane) << 3];
                acc2[mt] = __builtin_amdgcn_mfma_f32_16x16x32_bf16(afr, bfr, acc2[mt], 0, 0, 0);
            }
        }

        float v[4][4];
        float partial = 0.f;
#pragma unroll
        for (int mt = 0; mt < 4; ++mt) {
#pragma unroll
            for (int r = 0; r < 4; ++r) {
                const int tap = mt * 16 + quad * 4 + r;
                float val = (tap < 49) ? (acc2[mt][r] + b2[tap]) : 0.f;
                v[mt][r] = val;
                partial += val;
            }
        }
        partial += __shfl_xor(partial, 16, 64);
        partial += __shfl_xor(partial, 32, 64);
        const float m = partial * (1.f / 49.f) - (1.f / 49.f);

        const int b  = (int)(pix >> 14);
        const int hw = (int)(pix & 16383);
#pragma unroll
        for (int mt = 0; mt < 4; ++mt) {
#pragma unroll
            for (int r = 0; r < 4; ++r) {
                const int tap = mt * 16 + quad * 4 + r;
                if (tap < 49)
                    lpout[((size_t)b * 49 + tap) * HWc + hw] = f2bu(v[mt][r] - m);
            }
        }
    }
}

// ---------------------------------------------------------------------------
// conv2 fused (round-0 best): BOTH tiles DMA'd up-front into double LDS,
// ONE barrier, two GEMMs, feat = fp*mp -> bf16 NCHW planes.
// Producer-aligned XCD map. grid = 512 (1-D).
// ---------------------------------------------------------------------------
__global__ __launch_bounds__(256) void conv2_fused_k(
    const unsigned short* __restrict__ t1f,
    const unsigned short* __restrict__ t1m,
    const unsigned short* __restrict__ wf,
    const unsigned short* __restrict__ wm,
    const float* __restrict__ bf,
    const float* __restrict__ bm,
    const unsigned short* __restrict__ zpage,
    unsigned short* __restrict__ featp)
{
    __shared__ unsigned short s_b2[2][264 * 64];

    const int tid  = threadIdx.x;
    const int lane = tid & 63;
    const int wv   = tid >> 6;
    const int glin = blockIdx.x;
    const int xcd  = glin & 7;
    const int slot = glin >> 3;          // 0..63
    const int b    = xcd >> 1;
    const int w0   = (xcd & 1) * 64;
    const int h0   = slot * 2;

    STAGE_DMA(t1f, s_b2[0]);
    STAGE_DMA(t1m, s_b2[1]);
    __syncthreads();

    const int rowsel = wv >> 1;
    const int cohalf = wv & 1;
    const int quad   = lane >> 4;
    const int n15    = lane & 15;

    int rowb[3];
#pragma unroll
    for (int ky = 0; ky < 3; ++ky) rowb[ky] = (rowsel + ky) * 66 + n15;

    float4v acc[2][4];
#pragma unroll
    for (int m = 0; m < 2; ++m)
#pragma unroll
        for (int nt = 0; nt < 4; ++nt) acc[m][nt] = (float4v){0.f, 0.f, 0.f, 0.f};

    {
        const unsigned short* aptr = wf + (((size_t)(cohalf * 2) * 64 + lane) << 3);
        CONV_GEMM(aptr, acc, s_b2[0]);
    }

    float fpv[2][4][4];
#pragma unroll
    for (int m = 0; m < 2; ++m) {
        const int mt  = cohalf * 2 + m;
        const int co0 = mt * 16 + quad * 4;
        float4 bv = *(const float4*)&bf[co0];
#pragma unroll
        for (int nt = 0; nt < 4; ++nt) {
            fpv[m][nt][0] = bulo((unsigned int)f2bu(acc[m][nt][0] + bv.x));
            fpv[m][nt][1] = bulo((unsigned int)f2bu(acc[m][nt][1] + bv.y));
            fpv[m][nt][2] = bulo((unsigned int)f2bu(acc[m][nt][2] + bv.z));
            fpv[m][nt][3] = bulo((unsigned int)f2bu(acc[m][nt][3] + bv.w));
        }
    }

#pragma unroll
    for (int m = 0; m < 2; ++m)
#pragma unroll
        for (int nt = 0; nt < 4; ++nt) acc[m][nt] = (float4v){0.f, 0.f, 0.f, 0.f};

    {
        const unsigned short* aptr = wm + (((size_t)(cohalf * 2) * 64 + lane) << 3);
        CONV_GEMM(aptr, acc, s_b2[1]);
    }

    const int h = h0 + rowsel;
#pragma unroll
    for (int m = 0; m < 2; ++m) {
        const int mt  = cohalf * 2 + m;
        const int co0 = mt * 16 + quad * 4;
        float4 bv = *(const float4*)&bm[co0];
#pragma unroll
        for (int nt = 0; nt < 4; ++nt) {
            const int px = h * Wc + w0 + nt * 16 + n15;
            float v[4] = {acc[m][nt][0] + bv.x, acc[m][nt][1] + bv.y,
                          acc[m][nt][2] + bv.z, acc[m][nt][3] + bv.w};
#pragma unroll
            for (int r = 0; r < 4; ++r)
                featp[((size_t)b * Cc + co0 + r) * HWc + px] =
                    f2bu(v[r] * fpv[m][nt][r]);
        }
    }
}

// ---------------------------------------------------------------------------
// Dynamic local 7x7 conv + residual (round-0, unchanged).
// ---------------------------------------------------------------------------
__global__ __launch_bounds__(256) void local_conv_v4(
    const float* __restrict__ x, const unsigned short* __restrict__ featp,
    const unsigned short* __restrict__ lp, float* __restrict__ out)
{
    const int tid  = threadIdx.x;
    const int glin = blockIdx.x;
    const int xcd  = glin & 7;
    const int slot = glin >> 3;              // 0..127
    const int pair = xcd * 8 + (slot >> 4);  // 0..63
    const int cg   = slot & 15;
    const int b    = pair >> 4;
    const int hti  = pair & 15;

    const int w4  = (tid & 31) * 4;
    const int ro  = tid >> 5;
    const int h   = hti * 8 + ro;
    const int c0  = cg * 4;

    float msk[12];
#pragma unroll
    for (int e = 0; e < 12; ++e) {
        int gw = w4 - 4 + e;
        msk[e] = ((unsigned)gw < (unsigned)Wc) ? 1.f : 0.f;
    }

    float acc[4][4];
#pragma unroll
    for (int ch = 0; ch < 4; ++ch)
#pragma unroll
        for (int p = 0; p < 4; ++p) acc[ch][p] = 0.f;

    const unsigned short* lpb = lp + (size_t)b * 49 * HWc + (size_t)h * Wc + w4;
    const unsigned short* fb  = featp + ((size_t)b * Cc + c0) * HWc;

#pragma unroll
    for (int dy = 0; dy < 7; ++dy) {
        const int gh = h + dy - 3;
        if ((unsigned)gh >= (unsigned)Hc) continue;

        float lpf[7][4];
#pragma unroll
        for (int dx = 0; dx < 7; ++dx) {
            uint2 lv = *(const uint2*)&lpb[(size_t)(dy * 7 + dx) * HWc];
            lpf[dx][0] = bulo(lv.x); lpf[dx][1] = buhi(lv.x);
            lpf[dx][2] = bulo(lv.y); lpf[dx][3] = buhi(lv.y);
        }

        const unsigned short* frow = fb + (size_t)gh * Wc + w4;
#pragma unroll
        for (int ch = 0; ch < 4; ++ch) {
            const unsigned short* fr = frow + (size_t)ch * HWc;
            uint2 a  = *(const uint2*)(fr - 4);
            uint2 bq = *(const uint2*)(fr);
            uint2 cq = *(const uint2*)(fr + 4);
            float f[12];
            f[0]  = bulo(a.x);             f[1]  = buhi(a.x) * msk[1];
            f[2]  = bulo(a.y) * msk[2];    f[3]  = buhi(a.y) * msk[3];
            f[4]  = bulo(bq.x);            f[5]  = buhi(bq.x);
            f[6]  = bulo(bq.y);            f[7]  = buhi(bq.y);
            f[8]  = bulo(cq.x) * msk[8];   f[9]  = buhi(cq.x) * msk[9];
            f[10] = bulo(cq.y) * msk[10];  f[11] = buhi(cq.y);
#pragma unroll
            for (int dx = 0; dx < 7; ++dx)
#pragma unroll
                for (int p = 0; p < 4; ++p)
                    acc[ch][p] = fmaf(f[p + dx + 1], lpf[dx][p], acc[ch][p]);
        }
    }

#pragma unroll
    for (int ch = 0; ch < 4; ++ch) {
        const size_t idx = ((size_t)b * Cc + c0 + ch) * HWc + (size_t)h * Wc + w4;
        float4 xv = *(const float4*)&x[idx];
        float4 r  = {acc[ch][0] + xv.x, acc[ch][1] + xv.y,
                     acc[ch][2] + xv.z, acc[ch][3] + xv.w};
        *(float4*)&out[idx] = r;
    }
}

// ---------------------------------------------------------------------------
extern "C" void kernel_launch(void* const* d_in, const int* in_sizes, int n_in,
                              void* d_out, int out_size, void* d_ws, size_t ws_size,
                              hipStream_t stream)
{
    const float* x   = (const float*)d_in[0];
    const float* kf  = (const float*)d_in[1];
    const float* fw1 = (const float*)d_in[2];
    const float* fb1 = (const float*)d_in[3];
    const float* fw2 = (const float*)d_in[4];
    const float* fb2 = (const float*)d_in[5];
    const float* mw1 = (const float*)d_in[6];
    const float* mb1 = (const float*)d_in[7];
    const float* mw2 = (const float*)d_in[8];
    const float* mb2 = (const float*)d_in[9];
    const float* lw1 = (const float*)d_in[10];
    const float* lb1 = (const float*)d_in[11];
    const float* lw2 = (const float*)d_in[12];
    const float* lb2 = (const float*)d_in[13];

    float* out = (float*)d_out;
    char*  ws  = (char*)d_ws;

    const size_t NBH = (size_t)Bc * HWc * Cc * 2;   // bf16 tensor: 8.4 MB
    const size_t LPH = (size_t)Bc * 49 * HWc * 2;   // bf16 lp planes: 6.4 MB
    const size_t WBA = (size_t)(4 * 36864 + 2 * 4096) * 2;

    unsigned short* t1f   = (unsigned short*)(ws);
    unsigned short* t1m   = (unsigned short*)(ws + NBH);
    unsigned short* featp = (unsigned short*)(ws + 2 * NBH);
    unsigned short* lpb   = (unsigned short*)(ws + 3 * NBH);
    unsigned short* xb    = (unsigned short*)(ws + 3 * NBH + LPH);
    unsigned short* kfb   = (unsigned short*)((char*)xb + NBH);
    unsigned short* wbase = (unsigned short*)((char*)kfb + NBH);
    unsigned short* zpage = (unsigned short*)((char*)wbase + WBA);
    unsigned short* wb1   = wbase;
    unsigned short* wb2   = wbase + 36864;
    unsigned short* wb3   = wbase + 2 * 36864;
    unsigned short* wb4   = wbase + 3 * 36864;
    unsigned short* wl1   = wbase + 4 * 36864;
    unsigned short* wl2   = wbase + 4 * 36864 + 4096;

    dim3 blk(256);

    prep_k<<<dim3(589), blk, 0, stream>>>(x, kf, fw1, fw2, mw1, mw2, lw1, lw2,
                                          xb, kfb, wbase, zpage);

    conv1_lp_k<<<dim3(2048), blk, 0, stream>>>(xb, kfb, wb1, wb3, fb1, mb1, zpage,
                                               t1f, t1m, wl1, lb1, wl2, lb2, lpb);

    conv2_fused_k<<<dim3(512), blk, 0, stream>>>(t1f, t1m, wb2, wb4, fb2, mb2,
                                                 zpage, featp);

    local_conv_v4<<<dim3(1024), blk, 0, stream>>>(x, featp, lpb, out);
}